// Round 1
// baseline (69.044 us; speedup 1.0000x reference)
//
#include <hip/hip_runtime.h>
#include <hip/hip_bf16.h>

// Pairwise contrastive (InfoNCE-style) loss:
//   Xn = normalize(X), Yn = normalize(Y); logits = Xn@Yn^T / 0.07
//   loss = mean_i( lse_i - logits[i,i] ),  lse_i = logsumexp_j logits[i,j]
// Trick: logits <= 1/T, so use FIXED max M = 1/T: lse = 1/T + ln(sum exp(logit - 1/T)).
// No online-max, no rescale. sum in [~1e-3, ~1e-1] -> f32 safe.
//
// ws layout (needs ~8.2 MB):
//   [0,       4MB)   : Xn  bf16 [8192][256]
//   [4MB,     8MB)   : Yn  bf16 [8192][256]
//   [8MB,     +32KB) : diag f32 [8192]   (exact fp32 diagonal logits)
//   [8MB+32K, +32KB) : row_sum f32 [8192] (sum of exp over all columns)

typedef __attribute__((ext_vector_type(4))) float f32x4;
typedef __attribute__((ext_vector_type(8))) short s16x8;

#define AS1(p) ((const __attribute__((address_space(1))) void*)(uintptr_t)(p))
#define AS3(p) ((__attribute__((address_space(3))) void*)(uintptr_t)(p))

constexpr int   BROWS = 8192;
constexpr int   DDIM  = 256;
constexpr float kInvT = 14.285714285714286f;   // 1/0.07
constexpr float kC1   = 20.609929155556622f;   // log2(e)/0.07

static __device__ __forceinline__ unsigned short f2bf(float f) {
  // round-to-nearest-even f32 -> bf16 (inputs are finite normals here)
  unsigned u = __builtin_bit_cast(unsigned, f);
  unsigned rounding = 0x7FFFu + ((u >> 16) & 1u);
  return (unsigned short)((u + rounding) >> 16);
}

// ---------------- normalize rows + exact diagonal ----------------
// one wave per row-index i: normalizes X[i] and Y[i], writes bf16 rows,
// and diag[i] = dot(Xn_i, Yn_i)/T computed in exact fp32.
__global__ __launch_bounds__(256) void nrm_kernel(
    const float* __restrict__ X, const float* __restrict__ Y,
    unsigned short* __restrict__ Xn, unsigned short* __restrict__ Yn,
    float* __restrict__ diag)
{
  const int wave = threadIdx.x >> 6;
  const int lane = threadIdx.x & 63;
  const int row  = blockIdx.x * 4 + wave;
  const float4 x = *(const float4*)(X + (size_t)row * DDIM + lane * 4);
  const float4 y = *(const float4*)(Y + (size_t)row * DDIM + lane * 4);
  float ssx = x.x*x.x + x.y*x.y + x.z*x.z + x.w*x.w;
  float ssy = y.x*y.x + y.y*y.y + y.z*y.z + y.w*y.w;
  float dot = x.x*y.x + x.y*y.y + x.z*y.z + x.w*y.w;
  #pragma unroll
  for (int m = 1; m < 64; m <<= 1) {
    ssx += __shfl_xor(ssx, m);
    ssy += __shfl_xor(ssy, m);
    dot += __shfl_xor(dot, m);
  }
  const float invx = 1.0f / fmaxf(sqrtf(ssx), 1e-8f);
  const float invy = 1.0f / fmaxf(sqrtf(ssy), 1e-8f);
  ushort4 ox, oy;
  ox.x = f2bf(x.x * invx); ox.y = f2bf(x.y * invx);
  ox.z = f2bf(x.z * invx); ox.w = f2bf(x.w * invx);
  oy.x = f2bf(y.x * invy); oy.y = f2bf(y.y * invy);
  oy.z = f2bf(y.z * invy); oy.w = f2bf(y.w * invy);
  *(ushort4*)(Xn + (size_t)row * DDIM + lane * 4) = ox;
  *(ushort4*)(Yn + (size_t)row * DDIM + lane * 4) = oy;
  if (lane == 0) diag[row] = dot * invx * invy * kInvT;
}

// ---------------- main: exp-sum of logits over all columns ----------------
// grid = 32 row-panels x 16 col-splits = 512 blocks, 256 thr (4 waves).
// wave owns 64 rows: A frags (4 m x 8 ks) preloaded in registers.
// B tile (32 Y-rows x 256) double-buffered in LDS via global_load_lds,
// linear LDS + pre-swizzled source; reads XOR-swizzled (2-way instead of 16-way).
__global__ __launch_bounds__(256, 2) void logits_kernel(
    const unsigned short* __restrict__ Xn,
    const unsigned short* __restrict__ Yn,
    float* __restrict__ row_sum)
{
  __shared__ char lds[2 * 16384];
  const int tid  = threadIdx.x;
  const int lane = tid & 63;
  const int wave = tid >> 6;
  const int l15  = lane & 15;
  const int lhi  = lane >> 4;
  const int panel = blockIdx.x >> 4;   // 0..31
  const int split = blockIdx.x & 15;   // 0..15
  const int rowbase = panel * 256 + wave * 64;
  const char* Xb = (const char*)Xn;
  const char* Yb = (const char*)Yn + (size_t)split * (512 * 512); // 512 rows * 512B

  // A fragments: lane holds row (rowbase+16m+l15), k = 32*ks + 8*lhi .. +8
  s16x8 a[4][8];
  #pragma unroll
  for (int m = 0; m < 4; ++m) {
    const char* rp = Xb + (size_t)(rowbase + m * 16 + l15) * 512 + lhi * 16;
    #pragma unroll
    for (int ks = 0; ks < 8; ++ks)
      a[m][ks] = *(const s16x8*)(rp + ks * 64);
  }

  float sums[4][4] = {{0.f, 0.f, 0.f, 0.f}};
  const int xr = (l15 & 7) << 4;   // read-side XOR swizzle (same for n=0 and n=1 rows)

  // stage tile 0 into buffer 0
  #pragma unroll
  for (int s = 0; s < 4; ++s) {
    const int portion = (s * 4 + wave) * 1024;
    const int L = portion + lane * 16;
    const int src = L ^ (((L >> 9) & 7) << 4);
    __builtin_amdgcn_global_load_lds(AS1(Yb + src), AS3(lds + portion), 16, 0, 0);
  }
  __syncthreads();

  for (int j = 0; j < 16; ++j) {
    const int cur = j & 1;
    if (j + 1 < 16) {                    // prefetch next tile into other buffer
      const char* Yt = Yb + (size_t)(j + 1) * 16384;
      char* db = lds + (cur ^ 1) * 16384;
      #pragma unroll
      for (int s = 0; s < 4; ++s) {
        const int portion = (s * 4 + wave) * 1024;
        const int L = portion + lane * 16;
        const int src = L ^ (((L >> 9) & 7) << 4);
        __builtin_amdgcn_global_load_lds(AS1(Yt + src), AS3(db + portion), 16, 0, 0);
      }
    }
    const char* bb = lds + cur * 16384;
    f32x4 acc[4][2];
    #pragma unroll
    for (int m = 0; m < 4; ++m) {
      acc[m][0] = (f32x4){0.f, 0.f, 0.f, 0.f};
      acc[m][1] = (f32x4){0.f, 0.f, 0.f, 0.f};
    }
    #pragma unroll
    for (int ks = 0; ks < 8; ++ks) {
      const int c = ks * 64 + lhi * 16;
      const s16x8 b0 = *(const s16x8*)(bb + ((l15 * 512 + c) ^ xr));
      const s16x8 b1 = *(const s16x8*)(bb + ((((16 + l15) * 512) + c) ^ xr));
      #pragma unroll
      for (int m = 0; m < 4; ++m) {
        acc[m][0] = __builtin_amdgcn_mfma_f32_16x16x32_bf16(a[m][ks], b0, acc[m][0], 0, 0, 0);
        acc[m][1] = __builtin_amdgcn_mfma_f32_16x16x32_bf16(a[m][ks], b1, acc[m][1], 0, 0, 0);
      }
    }
    // softmax-sum with fixed max 1/T: e = 2^((cos-1)*log2(e)/T)
    #pragma unroll
    for (int m = 0; m < 4; ++m)
      #pragma unroll
      for (int r = 0; r < 4; ++r) {
        sums[m][r] += exp2f(__builtin_fmaf(acc[m][0][r], kC1, -kC1))
                    + exp2f(__builtin_fmaf(acc[m][1][r], kC1, -kC1));
      }
    __syncthreads();   // staged tile complete; all reads of cur done
  }

  // row-reduce across the 16 column-lanes, one atomic per row per split
  #pragma unroll
  for (int m = 0; m < 4; ++m)
    #pragma unroll
    for (int r = 0; r < 4; ++r) {
      float s = sums[m][r];
      s += __shfl_xor(s, 1);
      s += __shfl_xor(s, 2);
      s += __shfl_xor(s, 4);
      s += __shfl_xor(s, 8);
      if (l15 == 0)
        atomicAdd(row_sum + rowbase + m * 16 + lhi * 4 + r, s);
    }
}

// ---------------- final scalar: mean(1/T + ln(S_i) - diag_i) ----------------
__global__ __launch_bounds__(256) void loss_kernel(
    const float* __restrict__ row_sum, const float* __restrict__ diag,
    float* __restrict__ out)
{
  __shared__ double red[256];
  double acc = 0.0;
  for (int i = threadIdx.x; i < BROWS; i += 256)
    acc += (double)(kInvT + logf(row_sum[i]) - diag[i]);
  red[threadIdx.x] = acc;
  __syncthreads();
  for (int s = 128; s > 0; s >>= 1) {
    if (threadIdx.x < s) red[threadIdx.x] += red[threadIdx.x + s];
    __syncthreads();
  }
  if (threadIdx.x == 0) out[0] = (float)(red[0] / (double)BROWS);
}

extern "C" void kernel_launch(void* const* d_in, const int* in_sizes, int n_in,
                              void* d_out, int out_size, void* d_ws, size_t ws_size,
                              hipStream_t stream) {
  (void)in_sizes; (void)n_in; (void)out_size; (void)ws_size;
  const float* X = (const float*)d_in[0];
  const float* Y = (const float*)d_in[1];
  char* w = (char*)d_ws;
  unsigned short* Xn = (unsigned short*)(w);
  unsigned short* Yn = (unsigned short*)(w + (4u << 20));
  float* diag    = (float*)(w + (8u << 20));
  float* row_sum = (float*)(w + (8u << 20) + (32u << 10));

  hipMemsetAsync(row_sum, 0, BROWS * sizeof(float), stream);
  nrm_kernel<<<BROWS / 4, 256, 0, stream>>>(X, Y, Xn, Yn, diag);
  logits_kernel<<<512, 256, 0, stream>>>(Xn, Yn, row_sum);
  loss_kernel<<<1, 256, 0, stream>>>(row_sum, diag, (float*)d_out);
}

// Round 2
// 57.205 us; speedup vs baseline: 1.2070x; 1.2070x over previous
//
#include <hip/hip_runtime.h>
#include <hip/hip_bf16.h>

// InfoNCE-style loss: Xn=normalize(X), Yn=normalize(Y), logits=Xn@Yn^T/0.07,
// loss = mean_i(lse_i - logits[i,i]).
// Fixed-max trick: logits <= 1/T, so lse = 1/T + ln(sum_j exp(logit-1/T)).
//
// ws layout:
//   [0,4MB)        Xn bf16 [8192][256]
//   [4MB,8MB)      Yn bf16 [8192][256]
//   [8MB,+32KB)    diag f32[8192]
//   [8MB+32K,+32K) row_sum f32[8192]
//   [8MB+64K,+4)   loss accumulator f32

typedef __attribute__((ext_vector_type(4))) float f32x4;
typedef __attribute__((ext_vector_type(8))) short s16x8;

#define AS1(p) ((const __attribute__((address_space(1))) void*)(uintptr_t)(p))
#define AS3(p) ((__attribute__((address_space(3))) void*)(uintptr_t)(p))

constexpr int   BROWS = 8192;
constexpr int   DDIM  = 256;
constexpr float kInvT = 14.285714285714286f;   // 1/0.07
constexpr float kC1   = 20.609929155556622f;   // log2(e)/0.07
constexpr float kLn2  = 0.6931471805599453f;

#if __has_builtin(__builtin_amdgcn_exp2f)
#define EXP2F(x) __builtin_amdgcn_exp2f(x)
#else
#define EXP2F(x) exp2f(x)
#endif
#if __has_builtin(__builtin_amdgcn_logf)
#define LOG2F(x) __builtin_amdgcn_logf(x)
#else
#define LOG2F(x) log2f(x)
#endif

static __device__ __forceinline__ unsigned short f2bf(float f) {
  unsigned u = __builtin_bit_cast(unsigned, f);
  unsigned rounding = 0x7FFFu + ((u >> 16) & 1u);
  return (unsigned short)((u + rounding) >> 16);
}

// ---------------- normalize rows + exact fp32 diagonal ----------------
__global__ __launch_bounds__(256) void nrm_kernel(
    const float* __restrict__ X, const float* __restrict__ Y,
    unsigned short* __restrict__ Xn, unsigned short* __restrict__ Yn,
    float* __restrict__ diag)
{
  const int wave = threadIdx.x >> 6;
  const int lane = threadIdx.x & 63;
  const int row  = blockIdx.x * 4 + wave;
  const float4 x = *(const float4*)(X + (size_t)row * DDIM + lane * 4);
  const float4 y = *(const float4*)(Y + (size_t)row * DDIM + lane * 4);
  float ssx = x.x*x.x + x.y*x.y + x.z*x.z + x.w*x.w;
  float ssy = y.x*y.x + y.y*y.y + y.z*y.z + y.w*y.w;
  float dot = x.x*y.x + x.y*y.y + x.z*y.z + x.w*y.w;
  #pragma unroll
  for (int m = 1; m < 64; m <<= 1) {
    ssx += __shfl_xor(ssx, m);
    ssy += __shfl_xor(ssy, m);
    dot += __shfl_xor(dot, m);
  }
  const float invx = 1.0f / fmaxf(sqrtf(ssx), 1e-8f);
  const float invy = 1.0f / fmaxf(sqrtf(ssy), 1e-8f);
  ushort4 ox, oy;
  ox.x = f2bf(x.x * invx); ox.y = f2bf(x.y * invx);
  ox.z = f2bf(x.z * invx); ox.w = f2bf(x.w * invx);
  oy.x = f2bf(y.x * invy); oy.y = f2bf(y.y * invy);
  oy.z = f2bf(y.z * invy); oy.w = f2bf(y.w * invy);
  *(ushort4*)(Xn + (size_t)row * DDIM + lane * 4) = ox;
  *(ushort4*)(Yn + (size_t)row * DDIM + lane * 4) = oy;
  if (lane == 0) diag[row] = dot * invx * invy * kInvT;
}

// ---------------- main: exp-sum of logits over all columns ----------------
// 512 blocks x 256 thr (4 waves). Wave owns 64 X-rows, A in registers.
// B tile = 32 Y-rows x 256 (16KB), 4-deep LDS ring, global_load_lds staging
// (linear LDS dest + pre-swizzled source; XOR-swizzled reads).
// One vmcnt(0)+s_barrier per TWO tiles (counted-prefetch schedule):
//   pair p: [drain][barrier][issue 2p+2][compute 2p][issue 2p+3][compute 2p+1]
// Safety: barrier at p => all waves completed tiles 2p-2,2p-1, so their
// buffers ((2p+2)&3,(2p+3)&3) are free; the drain before the barrier means
// every wave's staged portions of tiles 2p,2p+1 have landed.
__global__ __launch_bounds__(256, 2) void logits_kernel(
    const unsigned short* __restrict__ Xn,
    const unsigned short* __restrict__ Yn,
    float* __restrict__ row_sum)
{
  __shared__ char lds[4 * 16384];
  const int tid  = threadIdx.x;
  const int lane = tid & 63;
  const int wave = tid >> 6;
  const int l15  = lane & 15;
  const int lhi  = lane >> 4;

  // XCD-aware bijective map: xcd=bid&7 owns 16 panels x 4 splits (~3MB/L2)
  const int bid  = blockIdx.x;
  const int xcd  = bid & 7;
  const int idx  = bid >> 3;                 // 0..63
  const int panel = (xcd >> 2) * 16 + (idx & 15);   // 0..31
  const int split = (xcd & 3) * 4 + (idx >> 4);     // 0..15

  const int rowbase = panel * 256 + wave * 64;
  const char* Xb = (const char*)Xn;
  const char* Yb = (const char*)Yn + (size_t)split * (512 * 512);

  // A fragments: lane holds row (rowbase+16m+l15), k = 32*ks + 8*lhi..+8
  s16x8 a[4][8];
  #pragma unroll
  for (int m = 0; m < 4; ++m) {
    const char* rp = Xb + (size_t)(rowbase + m * 16 + l15) * 512 + lhi * 16;
    #pragma unroll
    for (int ks = 0; ks < 8; ++ks)
      a[m][ks] = *(const s16x8*)(rp + ks * 64);
  }

  float sums[4][4] = {{0.f, 0.f, 0.f, 0.f}};
  const int xr = (l15 & 7) << 4;

  auto stage = [&](int t, int b) {
    const char* Yt = Yb + (size_t)t * 16384;
    char* db = lds + b * 16384;
    #pragma unroll
    for (int s = 0; s < 4; ++s) {
      const int portion = (s * 4 + wave) * 1024;
      const int L = portion + lane * 16;
      const int src = L ^ (((L >> 9) & 7) << 4);
      __builtin_amdgcn_global_load_lds(AS1(Yt + src), AS3(db + portion), 16, 0, 0);
    }
  };

  auto compute = [&](int b) {
    const char* bb = lds + b * 16384;
    f32x4 acc[4][2];
    #pragma unroll
    for (int m = 0; m < 4; ++m) {
      acc[m][0] = (f32x4){0.f, 0.f, 0.f, 0.f};
      acc[m][1] = (f32x4){0.f, 0.f, 0.f, 0.f};
    }
    __builtin_amdgcn_s_setprio(1);
    #pragma unroll
    for (int ks = 0; ks < 8; ++ks) {
      const int c = ks * 64 + lhi * 16;
      const s16x8 b0 = *(const s16x8*)(bb + ((l15 * 512 + c) ^ xr));
      const s16x8 b1 = *(const s16x8*)(bb + (((16 + l15) * 512 + c) ^ xr));
      #pragma unroll
      for (int m = 0; m < 4; ++m) {
        acc[m][0] = __builtin_amdgcn_mfma_f32_16x16x32_bf16(a[m][ks], b0, acc[m][0], 0, 0, 0);
        acc[m][1] = __builtin_amdgcn_mfma_f32_16x16x32_bf16(a[m][ks], b1, acc[m][1], 0, 0, 0);
      }
    }
    __builtin_amdgcn_s_setprio(0);
    #pragma unroll
    for (int m = 0; m < 4; ++m)
      #pragma unroll
      for (int r = 0; r < 4; ++r)
        sums[m][r] += EXP2F(__builtin_fmaf(acc[m][0][r], kC1, -kC1))
                    + EXP2F(__builtin_fmaf(acc[m][1][r], kC1, -kC1));
  };

  stage(0, 0);
  stage(1, 1);
  #pragma unroll 1
  for (int p = 0; p < 8; ++p) {
    const int j = 2 * p;
    asm volatile("s_waitcnt vmcnt(0)" ::: "memory");
    __builtin_amdgcn_s_barrier();
    if (j + 2 < 16) stage(j + 2, (j + 2) & 3);
    compute(j & 3);
    if (j + 3 < 16) stage(j + 3, (j + 3) & 3);
    compute((j + 1) & 3);
  }

  // reduce across the 16 column-lanes; one atomic per row per split
  #pragma unroll
  for (int m = 0; m < 4; ++m)
    #pragma unroll
    for (int r = 0; r < 4; ++r) {
      float s = sums[m][r];
      s += __shfl_xor(s, 1);
      s += __shfl_xor(s, 2);
      s += __shfl_xor(s, 4);
      s += __shfl_xor(s, 8);
      if (l15 == 0)
        atomicAdd(row_sum + rowbase + m * 16 + lhi * 4 + r, s);
    }
}

// ---------------- loss: parallel partial sums + finalize ----------------
__global__ __launch_bounds__(256) void loss_part(
    const float* __restrict__ row_sum, const float* __restrict__ diag,
    float* __restrict__ acc)
{
  const int i = blockIdx.x * 256 + threadIdx.x;
  float t = kInvT + LOG2F(row_sum[i]) * kLn2 - diag[i];
  #pragma unroll
  for (int m = 1; m < 64; m <<= 1) t += __shfl_xor(t, m);
  __shared__ float w[4];
  if ((threadIdx.x & 63) == 0) w[threadIdx.x >> 6] = t;
  __syncthreads();
  if (threadIdx.x == 0) atomicAdd(acc, w[0] + w[1] + w[2] + w[3]);
}

__global__ void loss_fin(const float* __restrict__ acc, float* __restrict__ out)
{
  out[0] = acc[0] * (1.0f / (float)BROWS);
}

extern "C" void kernel_launch(void* const* d_in, const int* in_sizes, int n_in,
                              void* d_out, int out_size, void* d_ws, size_t ws_size,
                              hipStream_t stream) {
  (void)in_sizes; (void)n_in; (void)out_size; (void)ws_size;
  const float* X = (const float*)d_in[0];
  const float* Y = (const float*)d_in[1];
  char* w = (char*)d_ws;
  unsigned short* Xn = (unsigned short*)(w);
  unsigned short* Yn = (unsigned short*)(w + (4u << 20));
  float* diag    = (float*)(w + (8u << 20));
  float* row_sum = (float*)(w + (8u << 20) + (32u << 10));
  float* acc     = (float*)(w + (8u << 20) + (64u << 10));

  hipMemsetAsync(row_sum, 0, BROWS * sizeof(float) + sizeof(float), stream);
  nrm_kernel<<<BROWS / 4, 256, 0, stream>>>(X, Y, Xn, Yn, diag);
  logits_kernel<<<512, 256, 0, stream>>>(Xn, Yn, row_sum);
  loss_part<<<BROWS / 256, 256, 0, stream>>>(row_sum, diag, acc);
  loss_fin<<<1, 1, 0, stream>>>(acc, (float*)d_out);
}

// Round 3
// 49.590 us; speedup vs baseline: 1.3923x; 1.1535x over previous
//
#include <hip/hip_runtime.h>
#include <hip/hip_bf16.h>

// InfoNCE-style loss: Xn=normalize(X), Yn=normalize(Y), logits=Xn@Yn^T/0.07,
// loss = mean_i(lse_i - logits[i,i]).
// Fixed-max trick: logits <= 1/T, so lse = 1/T + ln(sum_j exp(logit-1/T)).
//
// ws layout:
//   [0,4MB)        Xn bf16 [8192][256]
//   [4MB,8MB)      Yn bf16 [8192][256]
//   [8MB,+32KB)    diag f32[8192]
//   [8MB+32K,+32K) row_sum f32[8192]  (zeroed by nrm_kernel each call)

typedef __attribute__((ext_vector_type(4))) float f32x4;
typedef __attribute__((ext_vector_type(8))) short s16x8;

#define AS1(p) ((const __attribute__((address_space(1))) void*)(uintptr_t)(p))
#define AS3(p) ((__attribute__((address_space(3))) void*)(uintptr_t)(p))

constexpr int   BROWS = 8192;
constexpr int   DDIM  = 256;
constexpr float kInvT = 14.285714285714286f;   // 1/0.07
constexpr float kC1   = 20.609929155556622f;   // log2(e)/0.07
constexpr float kLn2  = 0.6931471805599453f;

#if __has_builtin(__builtin_amdgcn_exp2f)
#define EXP2F(x) __builtin_amdgcn_exp2f(x)
#else
#define EXP2F(x) exp2f(x)
#endif
#if __has_builtin(__builtin_amdgcn_logf)
#define LOG2F(x) __builtin_amdgcn_logf(x)
#else
#define LOG2F(x) log2f(x)
#endif

static __device__ __forceinline__ unsigned short f2bf(float f) {
  unsigned u = __builtin_bit_cast(unsigned, f);
  unsigned rounding = 0x7FFFu + ((u >> 16) & 1u);
  return (unsigned short)((u + rounding) >> 16);
}

// ---------------- normalize rows + exact fp32 diagonal + zero row_sum ------
__global__ __launch_bounds__(256) void nrm_kernel(
    const float* __restrict__ X, const float* __restrict__ Y,
    unsigned short* __restrict__ Xn, unsigned short* __restrict__ Yn,
    float* __restrict__ diag, float* __restrict__ row_sum)
{
  const int wave = threadIdx.x >> 6;
  const int lane = threadIdx.x & 63;
  const int row  = blockIdx.x * 4 + wave;
  const float4 x = *(const float4*)(X + (size_t)row * DDIM + lane * 4);
  const float4 y = *(const float4*)(Y + (size_t)row * DDIM + lane * 4);
  float ssx = x.x*x.x + x.y*x.y + x.z*x.z + x.w*x.w;
  float ssy = y.x*y.x + y.y*y.y + y.z*y.z + y.w*y.w;
  float dot = x.x*y.x + x.y*y.y + x.z*y.z + x.w*y.w;
  #pragma unroll
  for (int m = 1; m < 64; m <<= 1) {
    ssx += __shfl_xor(ssx, m);
    ssy += __shfl_xor(ssy, m);
    dot += __shfl_xor(dot, m);
  }
  const float invx = 1.0f / fmaxf(sqrtf(ssx), 1e-8f);
  const float invy = 1.0f / fmaxf(sqrtf(ssy), 1e-8f);
  ushort4 ox, oy;
  ox.x = f2bf(x.x * invx); ox.y = f2bf(x.y * invx);
  ox.z = f2bf(x.z * invx); ox.w = f2bf(x.w * invx);
  oy.x = f2bf(y.x * invy); oy.y = f2bf(y.y * invy);
  oy.z = f2bf(y.z * invy); oy.w = f2bf(y.w * invy);
  *(ushort4*)(Xn + (size_t)row * DDIM + lane * 4) = ox;
  *(ushort4*)(Yn + (size_t)row * DDIM + lane * 4) = oy;
  if (lane == 0) {
    diag[row] = dot * invx * invy * kInvT;
    row_sum[row] = 0.0f;   // replaces the hipMemsetAsync dispatch
  }
}

// -------- one B-tile of MFMAs with interleaved exp of the PREVIOUS tile ----
// cur/prev are distinct named arrays at each call site (static indexing).
// prev slice [ks>>1][ks&1] is exp-accumulated into sums and re-zeroed per
// ks-step, so `prev` is ready to be `cur` on the next tile.
__device__ __forceinline__ void tile_mfma(
    const char* __restrict__ bb, const s16x8 (&a)[4][8],
    f32x4 (&cur)[4][2], f32x4 (&prev)[4][2], float (&sums)[4][4],
    int baseE, int baseO)
{
  const char* pE = bb + baseE;
  const char* pO = bb + baseO;
  __builtin_amdgcn_s_setprio(1);
  #pragma unroll
  for (int ks = 0; ks < 8; ++ks) {
    const char* p = (ks & 1) ? pO : pE;
    const int off = (ks >> 1) * 128;
    const s16x8 b0 = *(const s16x8*)(p + off);
    const s16x8 b1 = *(const s16x8*)(p + off + 8192);
    #pragma unroll
    for (int m = 0; m < 4; ++m)
      cur[m][0] = __builtin_amdgcn_mfma_f32_16x16x32_bf16(a[m][ks], b0, cur[m][0], 0, 0, 0);
    #pragma unroll
    for (int m = 0; m < 4; ++m)
      cur[m][1] = __builtin_amdgcn_mfma_f32_16x16x32_bf16(a[m][ks], b1, cur[m][1], 0, 0, 0);
    const int pm = ks >> 1, pn = ks & 1;
    #pragma unroll
    for (int r = 0; r < 4; ++r)
      sums[pm][r] += EXP2F(__builtin_fmaf(prev[pm][pn][r], kC1, -kC1));
    prev[pm][pn] = (f32x4){0.f, 0.f, 0.f, 0.f};
  }
  __builtin_amdgcn_s_setprio(0);
}

// ---------------- main: exp-sum of logits over all columns ----------------
// 512 blocks x 256 thr (4 waves). Wave owns 64 X-rows, A in registers.
// B tile = 32 Y-rows x 256 (16KB), 4-deep LDS ring, global_load_lds staging
// (linear LDS dest + pre-swizzled source; XOR-swizzled static-offset reads).
// One vmcnt(0)+s_barrier per TWO tiles; acc double-buffer overlaps each
// tile's exp epilogue with the next tile's MFMA stream (T15 pattern).
__global__ __launch_bounds__(256, 2) void logits_kernel(
    const unsigned short* __restrict__ Xn,
    const unsigned short* __restrict__ Yn,
    float* __restrict__ row_sum)
{
  __shared__ char lds[4 * 16384];
  const int tid  = threadIdx.x;
  const int lane = tid & 63;
  const int wave = tid >> 6;
  const int l15  = lane & 15;
  const int lhi  = lane >> 4;

  // XCD-aware bijective map: xcd=bid&7 owns 16 panels x 4 splits (~3MB/L2)
  const int bid  = blockIdx.x;
  const int xcd  = bid & 7;
  const int idx  = bid >> 3;                        // 0..63
  const int panel = (xcd >> 2) * 16 + (idx & 15);   // 0..31
  const int split = (xcd & 3) * 4 + (idx >> 4);     // 0..15

  const int rowbase = panel * 256 + wave * 64;
  const char* Xb = (const char*)Xn;
  const char* Yb = (const char*)Yn + (size_t)split * (512 * 512);

  // A fragments: lane holds row (rowbase+16m+l15), k = 32*ks + 8*lhi..+8
  s16x8 a[4][8];
  #pragma unroll
  for (int m = 0; m < 4; ++m) {
    const char* rp = Xb + (size_t)(rowbase + m * 16 + l15) * 512 + lhi * 16;
    #pragma unroll
    for (int ks = 0; ks < 8; ++ks)
      a[m][ks] = *(const s16x8*)(rp + ks * 64);
  }

  float sums[4][4] = {{0.f, 0.f, 0.f, 0.f}};

  // Static swizzled read bases: addr(ks,n) = base{E,O} + (ks>>1)*128 + n*8192
  // (algebraic split of (l15*512 + ks*64 + lhi*16) ^ ((l15&7)<<4))
  const int xr    = (l15 & 7) << 4;
  const int sbase = l15 * 512 + ((lhi * 16) ^ (xr & 48));
  const int baseE = sbase + (xr & 64);
  const int baseO = sbase + ((xr & 64) ^ 64);

  auto stage = [&](int t, int b) {
    const char* Yt = Yb + (size_t)t * 16384;
    char* db = lds + b * 16384;
    #pragma unroll
    for (int s = 0; s < 4; ++s) {
      const int portion = (s * 4 + wave) * 1024;
      const int L = portion + lane * 16;
      const int src = L ^ (((L >> 9) & 7) << 4);
      __builtin_amdgcn_global_load_lds(AS1(Yt + src), AS3(db + portion), 16, 0, 0);
    }
  };

  // acc double-buffer: accA = cur of even tiles, accB = cur of odd tiles.
  // accB starts at -inf so tile 0's "prev" exp contributes exactly 0.
  f32x4 accA[4][2], accB[4][2];
  #pragma unroll
  for (int m = 0; m < 4; ++m)
    #pragma unroll
    for (int n = 0; n < 2; ++n) {
      accA[m][n] = (f32x4){0.f, 0.f, 0.f, 0.f};
      const float ni = -__builtin_inff();
      accB[m][n] = (f32x4){ni, ni, ni, ni};
    }

  stage(0, 0);
  stage(1, 1);
  #pragma unroll 1
  for (int p = 0; p < 8; ++p) {
    const int j = 2 * p;
    asm volatile("s_waitcnt vmcnt(0)" ::: "memory");
    __builtin_amdgcn_s_barrier();
    if (j + 2 < 16) stage(j + 2, (j + 2) & 3);
    tile_mfma(lds + (j & 3) * 16384, a, accA, accB, sums, baseE, baseO);
    if (j + 3 < 16) stage(j + 3, (j + 3) & 3);
    tile_mfma(lds + ((j + 1) & 3) * 16384, a, accB, accA, sums, baseE, baseO);
  }
  // flush tile 15 (its results live in accB)
  #pragma unroll
  for (int m = 0; m < 4; ++m)
    #pragma unroll
    for (int n = 0; n < 2; ++n)
      #pragma unroll
      for (int r = 0; r < 4; ++r)
        sums[m][r] += EXP2F(__builtin_fmaf(accB[m][n][r], kC1, -kC1));

  // reduce across the 16 column-lanes; one atomic per row per split
  #pragma unroll
  for (int m = 0; m < 4; ++m)
    #pragma unroll
    for (int r = 0; r < 4; ++r) {
      float s = sums[m][r];
      s += __shfl_xor(s, 1);
      s += __shfl_xor(s, 2);
      s += __shfl_xor(s, 4);
      s += __shfl_xor(s, 8);
      if (l15 == 0)
        atomicAdd(row_sum + rowbase + m * 16 + lhi * 4 + r, s);
    }
}

// ---------------- loss: single-kernel reduction ----------------
__global__ __launch_bounds__(1024) void loss_kernel(
    const float* __restrict__ row_sum, const float* __restrict__ diag,
    float* __restrict__ out)
{
  const int t = threadIdx.x;
  double acc = 0.0;
  #pragma unroll
  for (int h = 0; h < 2; ++h) {
    const int i = h * 4096 + t * 4;
    const float4 s = *(const float4*)(row_sum + i);
    const float4 d = *(const float4*)(diag + i);
    acc += (double)(kInvT + LOG2F(s.x) * kLn2 - d.x);
    acc += (double)(kInvT + LOG2F(s.y) * kLn2 - d.y);
    acc += (double)(kInvT + LOG2F(s.z) * kLn2 - d.z);
    acc += (double)(kInvT + LOG2F(s.w) * kLn2 - d.w);
  }
  #pragma unroll
  for (int m = 1; m < 64; m <<= 1) acc += __shfl_xor(acc, m);
  __shared__ double red[16];
  if ((t & 63) == 0) red[t >> 6] = acc;
  __syncthreads();
  if (t == 0) {
    double tot = 0.0;
    #pragma unroll
    for (int w = 0; w < 16; ++w) tot += red[w];
    out[0] = (float)(tot / (double)BROWS);
  }
}

extern "C" void kernel_launch(void* const* d_in, const int* in_sizes, int n_in,
                              void* d_out, int out_size, void* d_ws, size_t ws_size,
                              hipStream_t stream) {
  (void)in_sizes; (void)n_in; (void)out_size; (void)ws_size;
  const float* X = (const float*)d_in[0];
  const float* Y = (const float*)d_in[1];
  char* w = (char*)d_ws;
  unsigned short* Xn = (unsigned short*)(w);
  unsigned short* Yn = (unsigned short*)(w + (4u << 20));
  float* diag    = (float*)(w + (8u << 20));
  float* row_sum = (float*)(w + (8u << 20) + (32u << 10));

  nrm_kernel<<<BROWS / 4, 256, 0, stream>>>(X, Y, Xn, Yn, diag, row_sum);
  logits_kernel<<<512, 256, 0, stream>>>(Xn, Yn, row_sum);
  loss_kernel<<<1, 1024, 0, stream>>>(row_sum, diag, (float*)d_out);
}